// Round 1
// baseline (773.808 us; speedup 1.0000x reference)
//
#include <hip/hip_runtime.h>

// Problem constants
#define V_     32000
#define D_     4096
#define VIS_   768
#define MSK_   255
#define B_     2
#define T_     2048
#define TIMG_  128
#define R_     8
#define NLAT_  33
#define NTOK_  (B_ * T_)          // 4096 output rows
#define BASE_  (V_ + 4)           // 32004
#define IMG_END_ (BASE_ + TIMG_)  // 32132

struct Entry { int out_row; unsigned src; };  // src bit31: 0=base0 tensor, 1=base1 tensor; low 31 bits: float offset

// ---------------------------------------------------------------------------
// Kernel A: per-row gather + worklist build for special (computed) rows.
// grid = NTOK_ blocks, 256 threads. Gather rows copy 4096 f32 via float4.
// ---------------------------------------------------------------------------
__global__ __launch_bounds__(256) void gather_classify_kernel(
    const float* __restrict__ weight,
    const float* __restrict__ img_tok,
    const float* __restrict__ reg_tok,
    const int*   __restrict__ text,
    const int*   __restrict__ region2areas,
    float*       __restrict__ out,
    int*         __restrict__ counters,   // [0]=fc count, [1]=mask count
    Entry*       __restrict__ fcList,
    Entry*       __restrict__ mkList)
{
    const int row = blockIdx.x;                 // 0 .. NTOK_-1
    const int id  = text[row];
    const int b   = row >> 11;                  // row / T_ (T_=2048)

    const float* src;
    if (id < V_) {
        src = weight + (size_t)id * D_;
    } else if (id < V_ + 2) {
        src = img_tok + (size_t)(id - V_) * D_;
    } else if (id < BASE_) {
        src = reg_tok + (size_t)(id - (V_ + 2)) * D_;
    } else {
        // Special (computed) row: one lane appends to the worklist.
        if (threadIdx.x == 0) {
            const int id2 = id - BASE_;
            if (id2 < TIMG_) {
                int slot = atomicAdd(&counters[0], 1);
                fcList[slot].out_row = row;
                fcList[slot].src = (unsigned)((b * TIMG_ + id2) * VIS_);       // image_embedding_raw
            } else {
                const int j = id2 - TIMG_;          // 0 .. 263
                const int r = j / NLAT_;
                const int s = j - r * NLAT_;
                const int a = region2areas[b * R_ + r];
                if (s < 32) {
                    int slot = atomicAdd(&counters[0], 1);
                    fcList[slot].out_row = row;
                    fcList[slot].src = 0x80000000u |
                        (unsigned)(((b * R_ + a) * 32 + s) * VIS_);            // region_emb_raw
                } else {
                    int slot = atomicAdd(&counters[1], 1);
                    mkList[slot].out_row = row;
                    mkList[slot].src = (unsigned)((b * R_ + a) * MSK_);        // mask_emb_raw
                }
            }
        }
        return;
    }

    // Coalesced 16 KB row copy: 256 threads x 4 float4.
    const float4* s4 = (const float4*)src;
    float4*       o4 = (float4*)(out + (size_t)row * D_);
    const int t = threadIdx.x;
    o4[t]       = s4[t];
    o4[t + 256] = s4[t + 256];
    o4[t + 512] = s4[t + 512];
    o4[t + 768] = s4[t + 768];
}

// ---------------------------------------------------------------------------
// Kernel B: skinny matvec batch.  Y[m, col] = sum_k X[m,k] * W[k,col] + bias[col]
// Block = 256 threads = one 256-column stripe; MT=8 rows per tile in LDS.
// grid.x = D_/256 = 16 column stripes; grid.y = m-tile slots (grid-strided).
// W reads are coalesced (256 consecutive cols per k) and L2-resident.
// ---------------------------------------------------------------------------
template<int K>
__global__ __launch_bounds__(256) void matvec_kernel(
    const float* __restrict__ xbase0,   // image_embedding_raw (K=768) / mask_emb_raw (K=255)
    const float* __restrict__ xbase1,   // region_emb_raw (K=768) / unused (K=255)
    const float* __restrict__ W,        // K x D_
    const float* __restrict__ bias,     // D_
    float*       __restrict__ out,
    const int*   __restrict__ counter,
    const Entry* __restrict__ list)
{
    constexpr int MT = 8;
    __shared__ float xs[MT][K];
    __shared__ int   rows[MT];

    const int count = *counter;
    const int col   = blockIdx.x * 256 + threadIdx.x;

    for (int mt = blockIdx.y; mt * MT < count; mt += gridDim.y) {
        const int m0 = mt * MT;
        const int nm = min(MT, count - m0);

        __syncthreads();   // protect LDS from previous tile's readers
        for (int m = 0; m < nm; ++m) {
            Entry e = list[m0 + m];
            if (threadIdx.x == 0) rows[m] = e.out_row;
            const float* xp = (e.src & 0x80000000u)
                                ? (xbase1 + (e.src & 0x7fffffffu))
                                : (xbase0 + e.src);
            for (int k = threadIdx.x; k < K; k += 256) xs[m][k] = xp[k];
        }
        __syncthreads();

        float acc[MT];
        #pragma unroll
        for (int m = 0; m < MT; ++m) acc[m] = 0.0f;

        #pragma unroll 4
        for (int k = 0; k < K; ++k) {
            const float w = W[(size_t)k * D_ + col];
            #pragma unroll
            for (int m = 0; m < MT; ++m) acc[m] = fmaf(xs[m][k], w, acc[m]);
        }

        const float bv = bias[col];
        for (int m = 0; m < nm; ++m) {
            out[(size_t)rows[m] * D_ + col] = acc[m] + bv;
        }
    }
}

// ---------------------------------------------------------------------------
extern "C" void kernel_launch(void* const* d_in, const int* in_sizes, int n_in,
                              void* d_out, int out_size, void* d_ws, size_t ws_size,
                              hipStream_t stream)
{
    const float* weight    = (const float*)d_in[0];
    const float* img_tok   = (const float*)d_in[1];
    const float* reg_tok   = (const float*)d_in[2];
    const float* img_raw   = (const float*)d_in[3];
    const float* reg_raw   = (const float*)d_in[4];
    const float* msk_raw   = (const float*)d_in[5];
    const float* fc_w      = (const float*)d_in[6];
    const float* fc_b      = (const float*)d_in[7];
    const float* mask_fc_w = (const float*)d_in[8];
    const float* mask_fc_b = (const float*)d_in[9];
    const int*   text      = (const int*)d_in[10];
    const int*   r2a       = (const int*)d_in[11];
    float*       out       = (float*)d_out;

    // Workspace layout: [0,64): counters; then two worklists (max NTOK_ entries each).
    char* ws = (char*)d_ws;
    int*   counters = (int*)ws;
    Entry* fcList   = (Entry*)(ws + 64);
    Entry* mkList   = (Entry*)(ws + 64 + NTOK_ * sizeof(Entry));

    hipMemsetAsync(d_ws, 0, 64, stream);

    gather_classify_kernel<<<NTOK_, 256, 0, stream>>>(
        weight, img_tok, reg_tok, text, r2a, out, counters, fcList, mkList);

    // fc-type rows: K=768, expected count ~50.
    matvec_kernel<768><<<dim3(D_ / 256, 64), 256, 0, stream>>>(
        img_raw, reg_raw, fc_w, fc_b, out, &counters[0], fcList);

    // mask-type rows: K=255, expected count ~1.
    matvec_kernel<255><<<dim3(D_ / 256, 8), 256, 0, stream>>>(
        msk_raw, nullptr, mask_fc_w, mask_fc_b, out, &counters[1], mkList);
}